// Round 1
// baseline (1440.613 us; speedup 1.0000x reference)
//
#include <hip/hip_runtime.h>
#include <stdint.h>

#define T_TOK 8192
#define D_DIM 1024
#define F_DIM 4096
#define E_NUM 8
#define RCAP  17408   // 136 * 128 >= 16384 + 8*127 (per-expert 128-aligned regions)
#define MT    136

typedef __bf16 bf16;
typedef __bf16 bf16x8 __attribute__((ext_vector_type(8)));
typedef float  f32x4  __attribute__((ext_vector_type(4)));

typedef const __attribute__((address_space(1))) void* gptr1;
typedef __attribute__((address_space(3))) void* lptr3;

__device__ __forceinline__ void gload_lds16(const void* g, void* l) {
    // async global->LDS DMA, 16B/lane; LDS dest = wave-uniform base + lane*16
    __builtin_amdgcn_global_load_lds((gptr1)g, (lptr3)l, 16, 0, 0);
}

__device__ __forceinline__ unsigned short f2b(float f) {
    // fp32 -> bf16 round-to-nearest-even
    uint32_t u = __float_as_uint(f);
    u = (u + 0x7FFFu + ((u >> 16) & 1u)) >> 16;
    return (unsigned short)u;
}

// ---------------------------------------------------------------------------
// Transpose-convert: src fp32 [E][R][C] -> dst bf16 [E][C][R]
// ---------------------------------------------------------------------------
__global__ __launch_bounds__(256) void trans_kernel(const float* __restrict__ src,
                                                    bf16* __restrict__ dst,
                                                    int R, int C) {
    __shared__ unsigned short lt[64 * 72];   // stride 72 shorts = 144B (16B-aligned rows)
    const int e  = blockIdx.z;
    const int c0 = blockIdx.x * 64;
    const int r0 = blockIdx.y * 64;
    const float* s = src + (size_t)e * R * C;
    unsigned short* dp = (unsigned short*)dst + (size_t)e * R * C;
    const int t  = threadIdx.x;
    const int tr = t >> 4;
    const int tc = (t & 15) * 4;
    #pragma unroll
    for (int rr = 0; rr < 4; ++rr) {
        const int r = tr + rr * 16;
        const float4 v = *(const float4*)(s + (size_t)(r0 + r) * C + c0 + tc);
        lt[(tc + 0) * 72 + r] = f2b(v.x);
        lt[(tc + 1) * 72 + r] = f2b(v.y);
        lt[(tc + 2) * 72 + r] = f2b(v.z);
        lt[(tc + 3) * 72 + r] = f2b(v.w);
    }
    __syncthreads();
    const int oc  = t >> 2;
    const int seg = (t & 3) * 16;
    const uint4 a = *(const uint4*)&lt[oc * 72 + seg];
    const uint4 b = *(const uint4*)&lt[oc * 72 + seg + 8];
    unsigned short* orow = dp + (size_t)(c0 + oc) * R + (r0 + seg);
    *(uint4*)(orow)     = a;
    *(uint4*)(orow + 8) = b;
}

// ---------------------------------------------------------------------------
// Gate: fp32 logits (wave per token), top-2, softmax, per-expert counts
// ---------------------------------------------------------------------------
__global__ __launch_bounds__(256) void gate_kernel(const float* __restrict__ x,
                                                   const float* __restrict__ gw,
                                                   int* __restrict__ tki,
                                                   float* __restrict__ tkw,
                                                   int* __restrict__ counts) {
    const int t    = blockIdx.x * 4 + (threadIdx.x >> 6);
    const int lane = threadIdx.x & 63;
    const float* xr = x + (size_t)t * D_DIM;
    float acc[E_NUM];
    #pragma unroll
    for (int e = 0; e < E_NUM; ++e) acc[e] = 0.f;
    for (int j = 0; j < 16; ++j) {
        const int d = lane + 64 * j;
        const float xv = xr[d];
        const float* g = gw + (size_t)d * E_NUM;
        #pragma unroll
        for (int e = 0; e < E_NUM; ++e) acc[e] += xv * g[e];
    }
    #pragma unroll
    for (int off = 32; off >= 1; off >>= 1) {
        #pragma unroll
        for (int e = 0; e < E_NUM; ++e) acc[e] += __shfl_xor(acc[e], off);
    }
    if (lane == 0) {
        int b0 = 0; float v0 = acc[0];
        #pragma unroll
        for (int e = 1; e < E_NUM; ++e) if (acc[e] > v0) { v0 = acc[e]; b0 = e; }
        int b1 = -1; float v1 = -1e30f;
        #pragma unroll
        for (int e = 0; e < E_NUM; ++e) if (e != b0 && acc[e] > v1) { v1 = acc[e]; b1 = e; }
        const float ex = expf(v1 - v0);           // v1 <= v0
        const float w0 = 1.f / (1.f + ex);
        const float w1 = ex * w0;
        tki[t * 2]     = b0;  tkw[t * 2]     = w0;
        tki[t * 2 + 1] = b1;  tkw[t * 2 + 1] = w1;
        atomicAdd(&counts[b0], 1);
        atomicAdd(&counts[b1], 1);
    }
}

// ---------------------------------------------------------------------------
// Scan: 128-aligned exclusive offsets per expert
// ---------------------------------------------------------------------------
__global__ void scan_kernel(const int* __restrict__ counts, int* __restrict__ aoff,
                            int* __restrict__ cursor) {
    if (threadIdx.x == 0) {
        int off = 0;
        #pragma unroll
        for (int e = 0; e < E_NUM; ++e) {
            aoff[e]   = off;
            cursor[e] = off;
            off += (counts[e] + 127) & ~127;
        }
        aoff[E_NUM] = off;
    }
}

// ---------------------------------------------------------------------------
// Gather: assign permuted rows, copy+convert x rows to bf16 (wave per slot)
// ---------------------------------------------------------------------------
__global__ __launch_bounds__(256) void gather_kernel(const float* __restrict__ x,
                                                     const int* __restrict__ tki,
                                                     const float* __restrict__ tkw,
                                                     int* __restrict__ cursor,
                                                     int* __restrict__ ptok,
                                                     float* __restrict__ pwgt,
                                                     bf16* __restrict__ xp) {
    const int slot = blockIdx.x * 4 + (threadIdx.x >> 6);
    const int lane = threadIdx.x & 63;
    const int t = slot >> 1;
    int row = 0;
    if (lane == 0) {
        const int e = tki[slot];
        row = atomicAdd(&cursor[e], 1);
        ptok[row] = t;
        pwgt[row] = tkw[slot];
    }
    row = __shfl(row, 0);
    const float* xr = x + (size_t)t * D_DIM + lane * 16;
    unsigned short* dst = (unsigned short*)xp + (size_t)row * D_DIM + lane * 16;
    uint32_t u[8];
    #pragma unroll
    for (int q = 0; q < 4; ++q) {
        const float4 v = *(const float4*)(xr + q * 4);
        u[q * 2]     = (uint32_t)f2b(v.x) | ((uint32_t)f2b(v.y) << 16);
        u[q * 2 + 1] = (uint32_t)f2b(v.z) | ((uint32_t)f2b(v.w) << 16);
    }
    ((uint4*)dst)[0] = make_uint4(u[0], u[1], u[2], u[3]);
    ((uint4*)dst)[1] = make_uint4(u[4], u[5], u[6], u[7]);
}

// ---------------------------------------------------------------------------
// GEMM1: h = silu(Xp @ W1) * (Xp @ W3), dual-B 128x128x32, bf16 MFMA
//   xp [RCAP][D] bf16, wb1t/wb3t [E][F][D] bf16 (B^T), hb [RCAP][F] bf16
// ---------------------------------------------------------------------------
__global__ __launch_bounds__(256, 2) void gemm1_kernel(const bf16* __restrict__ xp,
                                                       const bf16* __restrict__ wb1t,
                                                       const bf16* __restrict__ wb3t,
                                                       bf16* __restrict__ hb,
                                                       const int* __restrict__ aoff,
                                                       const int* __restrict__ counts) {
    __shared__ bf16 As[128 * 32];
    __shared__ bf16 Bs1[128 * 32];
    __shared__ bf16 Bs3[128 * 32];

    const int m_base = blockIdx.y * 128;
    int e = 0;
    #pragma unroll
    for (int i = 1; i < E_NUM; ++i) if (m_base >= aoff[i]) e = i;
    if (m_base - aoff[e] >= counts[e]) return;

    const int nt   = blockIdx.x;
    const int tid  = threadIdx.x;
    const int w    = tid >> 6;
    const int lane = tid & 63;
    const int wm   = w & 1, wn = w >> 1;

    const bf16* Ab = xp + (size_t)m_base * D_DIM;
    const bf16* B1 = wb1t + ((size_t)e * F_DIM + (size_t)nt * 128) * D_DIM;
    const bf16* B3 = wb3t + ((size_t)e * F_DIM + (size_t)nt * 128) * D_DIM;

    const int srow    = w * 32 + (lane >> 2);  // staging row (j adds 16)
    const int scol    = (lane & 3) * 8;        // staging col (elems)
    const int ldsbase = w * 1024;              // elems (j adds 512)
    const int fm = lane & 15;
    const int fk = (lane >> 4) * 8;

    f32x4 acc1[4][4] = {};
    f32x4 acc3[4][4] = {};

    for (int kt = 0; kt < D_DIM / 32; ++kt) {
        const int k0 = kt * 32;
        #pragma unroll
        for (int j = 0; j < 2; ++j) {
            const size_t go = (size_t)(srow + j * 16) * D_DIM + (k0 + scol);
            gload_lds16(Ab + go, &As[ldsbase + j * 512]);
            gload_lds16(B1 + go, &Bs1[ldsbase + j * 512]);
            gload_lds16(B3 + go, &Bs3[ldsbase + j * 512]);
        }
        __syncthreads();
        bf16x8 af[4], b1f[4], b3f[4];
        #pragma unroll
        for (int i = 0; i < 4; ++i) {
            af[i]  = *(const bf16x8*)&As [(wm * 64 + i * 16 + fm) * 32 + fk];
            b1f[i] = *(const bf16x8*)&Bs1[(wn * 64 + i * 16 + fm) * 32 + fk];
            b3f[i] = *(const bf16x8*)&Bs3[(wn * 64 + i * 16 + fm) * 32 + fk];
        }
        #pragma unroll
        for (int i = 0; i < 4; ++i) {
            #pragma unroll
            for (int jn = 0; jn < 4; ++jn) {
                acc1[i][jn] = __builtin_amdgcn_mfma_f32_16x16x32_bf16(af[i], b1f[jn], acc1[i][jn], 0, 0, 0);
                acc3[i][jn] = __builtin_amdgcn_mfma_f32_16x16x32_bf16(af[i], b3f[jn], acc3[i][jn], 0, 0, 0);
            }
        }
        __syncthreads();
    }

    // epilogue: silu(s1)*s3 -> bf16  (C/D layout: col=lane&15, row=(lane>>4)*4+reg)
    unsigned short* hw = (unsigned short*)hb;
    #pragma unroll
    for (int i = 0; i < 4; ++i) {
        const int rbase = m_base + wm * 64 + i * 16 + (lane >> 4) * 4;
        #pragma unroll
        for (int jn = 0; jn < 4; ++jn) {
            const int col = nt * 128 + wn * 64 + jn * 16 + (lane & 15);
            #pragma unroll
            for (int r = 0; r < 4; ++r) {
                const float s1 = acc1[i][jn][r];
                const float s3 = acc3[i][jn][r];
                const float hv = (s1 / (1.0f + __expf(-s1))) * s3;
                hw[(size_t)(rbase + r) * F_DIM + col] = f2b(hv);
            }
        }
    }
}

// ---------------------------------------------------------------------------
// GEMM2: out[token] += wgt * (H @ W2), scatter via fp32 atomics
//   hb [RCAP][F] bf16, wb2t [E][D][F] bf16 (B^T), out [T][D] fp32
// ---------------------------------------------------------------------------
__global__ __launch_bounds__(256, 2) void gemm2_kernel(const bf16* __restrict__ hb,
                                                       const bf16* __restrict__ wb2t,
                                                       float* __restrict__ out,
                                                       const int* __restrict__ aoff,
                                                       const int* __restrict__ counts,
                                                       const int* __restrict__ ptok,
                                                       const float* __restrict__ pwgt) {
    __shared__ bf16 As[128 * 32];
    __shared__ bf16 Bs[128 * 32];

    const int m_base = blockIdx.y * 128;
    int e = 0;
    #pragma unroll
    for (int i = 1; i < E_NUM; ++i) if (m_base >= aoff[i]) e = i;
    if (m_base - aoff[e] >= counts[e]) return;

    const int nt   = blockIdx.x;
    const int tid  = threadIdx.x;
    const int w    = tid >> 6;
    const int lane = tid & 63;
    const int wm   = w & 1, wn = w >> 1;

    const bf16* Ab = hb + (size_t)m_base * F_DIM;
    const bf16* Bb = wb2t + ((size_t)e * D_DIM + (size_t)nt * 128) * F_DIM;

    const int srow    = w * 32 + (lane >> 2);
    const int scol    = (lane & 3) * 8;
    const int ldsbase = w * 1024;
    const int fm = lane & 15;
    const int fk = (lane >> 4) * 8;

    f32x4 acc[4][4] = {};

    for (int kt = 0; kt < F_DIM / 32; ++kt) {
        const int k0 = kt * 32;
        #pragma unroll
        for (int j = 0; j < 2; ++j) {
            const size_t go = (size_t)(srow + j * 16) * F_DIM + (k0 + scol);
            gload_lds16(Ab + go, &As[ldsbase + j * 512]);
            gload_lds16(Bb + go, &Bs[ldsbase + j * 512]);
        }
        __syncthreads();
        bf16x8 af[4], bfr[4];
        #pragma unroll
        for (int i = 0; i < 4; ++i) {
            af[i]  = *(const bf16x8*)&As[(wm * 64 + i * 16 + fm) * 32 + fk];
            bfr[i] = *(const bf16x8*)&Bs[(wn * 64 + i * 16 + fm) * 32 + fk];
        }
        #pragma unroll
        for (int i = 0; i < 4; ++i) {
            #pragma unroll
            for (int jn = 0; jn < 4; ++jn) {
                acc[i][jn] = __builtin_amdgcn_mfma_f32_16x16x32_bf16(af[i], bfr[jn], acc[i][jn], 0, 0, 0);
            }
        }
        __syncthreads();
    }

    #pragma unroll
    for (int i = 0; i < 4; ++i) {
        const int rb = m_base + wm * 64 + i * 16 + (lane >> 4) * 4;
        #pragma unroll
        for (int r = 0; r < 4; ++r) {
            const int row = rb + r;
            const int tok = ptok[row];
            if (tok < 0) continue;          // padding row
            const float wgt = pwgt[row];
            float* orow = out + (size_t)tok * D_DIM;
            #pragma unroll
            for (int jn = 0; jn < 4; ++jn) {
                const int col = nt * 128 + wn * 64 + jn * 16 + (lane & 15);
                atomicAdd(&orow[col], acc[i][jn][r] * wgt);
            }
        }
    }
}

// ---------------------------------------------------------------------------
extern "C" void kernel_launch(void* const* d_in, const int* in_sizes, int n_in,
                              void* d_out, int out_size, void* d_ws, size_t ws_size,
                              hipStream_t stream) {
    const float* x  = (const float*)d_in[0];
    const float* gw = (const float*)d_in[1];
    const float* w1 = (const float*)d_in[2];
    const float* w3 = (const float*)d_in[3];
    const float* w2 = (const float*)d_in[4];
    float* out = (float*)d_out;

    char* ws = (char*)d_ws;
    size_t off = 0;
    bf16* wb1t = (bf16*)(ws + off);                      // [E][F][D]
    bf16* wb2t = wb1t;                                   // aliased: w2^T built after gemm1
    off += (size_t)E_NUM * F_DIM * D_DIM * 2;
    bf16* wb3t = (bf16*)(ws + off); off += (size_t)E_NUM * F_DIM * D_DIM * 2;  // [E][F][D]
    bf16* xp   = (bf16*)(ws + off); off += (size_t)RCAP * D_DIM * 2;           // [RCAP][D]
    bf16* hb   = (bf16*)(ws + off); off += (size_t)RCAP * F_DIM * 2;           // [RCAP][F]
    int*   tki = (int*)(ws + off);   off += (size_t)T_TOK * 2 * 4;
    float* tkw = (float*)(ws + off); off += (size_t)T_TOK * 2 * 4;
    int* counts = (int*)(ws + off);  off += 64;
    int* cursor = (int*)(ws + off);  off += 64;
    int* aoff   = (int*)(ws + off);  off += 64;
    int* ptok   = (int*)(ws + off);  off += (size_t)RCAP * 4;
    float* pwgt = (float*)(ws + off); off += (size_t)RCAP * 4;

    hipMemsetAsync(out, 0, (size_t)T_TOK * D_DIM * 4, stream);
    hipMemsetAsync(counts, 0, 64, stream);
    hipMemsetAsync(ptok, 0xFF, (size_t)RCAP * 4, stream);   // pad rows -> token -1

    gate_kernel<<<T_TOK / 4, 256, 0, stream>>>(x, gw, tki, tkw, counts);
    scan_kernel<<<1, 64, 0, stream>>>(counts, aoff, cursor);
    gather_kernel<<<(T_TOK * 2) / 4, 256, 0, stream>>>(x, tki, tkw, cursor, ptok, pwgt, xp);

    trans_kernel<<<dim3(F_DIM / 64, D_DIM / 64, E_NUM), 256, 0, stream>>>(w1, wb1t, D_DIM, F_DIM);
    trans_kernel<<<dim3(F_DIM / 64, D_DIM / 64, E_NUM), 256, 0, stream>>>(w3, wb3t, D_DIM, F_DIM);

    gemm1_kernel<<<dim3(F_DIM / 128, MT), 256, 0, stream>>>(xp, wb1t, wb3t, hb, aoff, counts);

    trans_kernel<<<dim3(D_DIM / 64, F_DIM / 64, E_NUM), 256, 0, stream>>>(w2, wb2t, F_DIM, D_DIM);

    gemm2_kernel<<<dim3(D_DIM / 128, MT), 256, 0, stream>>>(hb, wb2t, out, aoff, counts, ptok, pwgt);
}

// Round 2
// 1402.234 us; speedup vs baseline: 1.0274x; 1.0274x over previous
//
#include <hip/hip_runtime.h>
#include <stdint.h>

#define T_TOK 8192
#define D_DIM 1024
#define F_DIM 4096
#define E_NUM 8
#define RCAP  17408   // 136 * 128 >= 16384 + 8*127 (per-expert 128-aligned regions)
#define MT    136

typedef __bf16 bf16;
typedef __bf16 bf16x8 __attribute__((ext_vector_type(8)));
typedef float  f32x4  __attribute__((ext_vector_type(4)));

typedef const __attribute__((address_space(1))) void* gptr1;
typedef __attribute__((address_space(3))) void* lptr3;

__device__ __forceinline__ void gload_lds16(const void* g, void* l) {
    // async global->LDS DMA, 16B/lane; LDS dest = wave-uniform base + lane*16
    __builtin_amdgcn_global_load_lds((gptr1)g, (lptr3)l, 16, 0, 0);
}

__device__ __forceinline__ unsigned short f2b(float f) {
    // fp32 -> bf16 round-to-nearest-even
    uint32_t u = __float_as_uint(f);
    u = (u + 0x7FFFu + ((u >> 16) & 1u)) >> 16;
    return (unsigned short)u;
}

// ---------------------------------------------------------------------------
// Transpose-convert: src fp32 [E][R][C] -> dst bf16 [E][C][R]
// ---------------------------------------------------------------------------
__global__ __launch_bounds__(256) void trans_kernel(const float* __restrict__ src,
                                                    bf16* __restrict__ dst,
                                                    int R, int C) {
    __shared__ unsigned short lt[64 * 72];   // stride 72 shorts = 144B (16B-aligned rows)
    const int e  = blockIdx.z;
    const int c0 = blockIdx.x * 64;
    const int r0 = blockIdx.y * 64;
    const float* s = src + (size_t)e * R * C;
    unsigned short* dp = (unsigned short*)dst + (size_t)e * R * C;
    const int t  = threadIdx.x;
    const int tr = t >> 4;
    const int tc = (t & 15) * 4;
    #pragma unroll
    for (int rr = 0; rr < 4; ++rr) {
        const int r = tr + rr * 16;
        const float4 v = *(const float4*)(s + (size_t)(r0 + r) * C + c0 + tc);
        lt[(tc + 0) * 72 + r] = f2b(v.x);
        lt[(tc + 1) * 72 + r] = f2b(v.y);
        lt[(tc + 2) * 72 + r] = f2b(v.z);
        lt[(tc + 3) * 72 + r] = f2b(v.w);
    }
    __syncthreads();
    const int oc  = t >> 2;
    const int seg = (t & 3) * 16;
    const uint4 a = *(const uint4*)&lt[oc * 72 + seg];
    const uint4 b = *(const uint4*)&lt[oc * 72 + seg + 8];
    unsigned short* orow = dp + (size_t)(c0 + oc) * R + (r0 + seg);
    *(uint4*)(orow)     = a;
    *(uint4*)(orow + 8) = b;
}

// ---------------------------------------------------------------------------
// Gate: fp32 logits (wave per token), top-2, softmax, per-expert counts
// ---------------------------------------------------------------------------
__global__ __launch_bounds__(256) void gate_kernel(const float* __restrict__ x,
                                                   const float* __restrict__ gw,
                                                   int* __restrict__ tki,
                                                   float* __restrict__ tkw,
                                                   int* __restrict__ counts) {
    const int t    = blockIdx.x * 4 + (threadIdx.x >> 6);
    const int lane = threadIdx.x & 63;
    const float* xr = x + (size_t)t * D_DIM;
    float acc[E_NUM];
    #pragma unroll
    for (int e = 0; e < E_NUM; ++e) acc[e] = 0.f;
    for (int j = 0; j < 16; ++j) {
        const int d = lane + 64 * j;
        const float xv = xr[d];
        const float* g = gw + (size_t)d * E_NUM;
        #pragma unroll
        for (int e = 0; e < E_NUM; ++e) acc[e] += xv * g[e];
    }
    #pragma unroll
    for (int off = 32; off >= 1; off >>= 1) {
        #pragma unroll
        for (int e = 0; e < E_NUM; ++e) acc[e] += __shfl_xor(acc[e], off);
    }
    if (lane == 0) {
        int b0 = 0; float v0 = acc[0];
        #pragma unroll
        for (int e = 1; e < E_NUM; ++e) if (acc[e] > v0) { v0 = acc[e]; b0 = e; }
        int b1 = -1; float v1 = -1e30f;
        #pragma unroll
        for (int e = 0; e < E_NUM; ++e) if (e != b0 && acc[e] > v1) { v1 = acc[e]; b1 = e; }
        const float ex = expf(v1 - v0);           // v1 <= v0
        const float w0 = 1.f / (1.f + ex);
        const float w1 = ex * w0;
        tki[t * 2]     = b0;  tkw[t * 2]     = w0;
        tki[t * 2 + 1] = b1;  tkw[t * 2 + 1] = w1;
        atomicAdd(&counts[b0], 1);
        atomicAdd(&counts[b1], 1);
    }
}

// ---------------------------------------------------------------------------
// Scan: 128-aligned exclusive offsets per expert
// ---------------------------------------------------------------------------
__global__ void scan_kernel(const int* __restrict__ counts, int* __restrict__ aoff,
                            int* __restrict__ cursor) {
    if (threadIdx.x == 0) {
        int off = 0;
        #pragma unroll
        for (int e = 0; e < E_NUM; ++e) {
            aoff[e]   = off;
            cursor[e] = off;
            off += (counts[e] + 127) & ~127;
        }
        aoff[E_NUM] = off;
    }
}

// ---------------------------------------------------------------------------
// Gather: assign permuted rows, record slot->row, convert x rows to bf16
// ---------------------------------------------------------------------------
__global__ __launch_bounds__(256) void gather_kernel(const float* __restrict__ x,
                                                     const int* __restrict__ tki,
                                                     int* __restrict__ cursor,
                                                     int* __restrict__ s2r,
                                                     bf16* __restrict__ xp) {
    const int slot = blockIdx.x * 4 + (threadIdx.x >> 6);
    const int lane = threadIdx.x & 63;
    const int t = slot >> 1;
    int row = 0;
    if (lane == 0) {
        const int e = tki[slot];
        row = atomicAdd(&cursor[e], 1);
        s2r[slot] = row;
    }
    row = __shfl(row, 0);
    const float* xr = x + (size_t)t * D_DIM + lane * 16;
    unsigned short* dst = (unsigned short*)xp + (size_t)row * D_DIM + lane * 16;
    uint32_t u[8];
    #pragma unroll
    for (int q = 0; q < 4; ++q) {
        const float4 v = *(const float4*)(xr + q * 4);
        u[q * 2]     = (uint32_t)f2b(v.x) | ((uint32_t)f2b(v.y) << 16);
        u[q * 2 + 1] = (uint32_t)f2b(v.z) | ((uint32_t)f2b(v.w) << 16);
    }
    ((uint4*)dst)[0] = make_uint4(u[0], u[1], u[2], u[3]);
    ((uint4*)dst)[1] = make_uint4(u[4], u[5], u[6], u[7]);
}

// ---------------------------------------------------------------------------
// GEMM1: h = silu(Xp @ W1) * (Xp @ W3), dual-B 128x128x32, bf16 MFMA
//   LDS k-group XOR swizzle: physical cg = logical cg ^ ((row>>1)&3).
//   Swizzle is applied on the GLOBAL source column (global_load_lds's LDS dest
//   is pinned to lane*16B), and folds into compile-time lane constants.
// ---------------------------------------------------------------------------
__global__ __launch_bounds__(256, 2) void gemm1_kernel(const bf16* __restrict__ xp,
                                                       const bf16* __restrict__ wb1t,
                                                       const bf16* __restrict__ wb3t,
                                                       bf16* __restrict__ hb,
                                                       const int* __restrict__ aoff,
                                                       const int* __restrict__ counts) {
    __shared__ bf16 As[128 * 32];
    __shared__ bf16 Bs1[128 * 32];
    __shared__ bf16 Bs3[128 * 32];

    const int m_base = blockIdx.y * 128;
    int e = 0;
    #pragma unroll
    for (int i = 1; i < E_NUM; ++i) if (m_base >= aoff[i]) e = i;
    if (m_base - aoff[e] >= counts[e]) return;

    const int nt   = blockIdx.x;
    const int tid  = threadIdx.x;
    const int w    = tid >> 6;
    const int lane = tid & 63;
    const int wm   = w & 1, wn = w >> 1;

    const bf16* Ab = xp + (size_t)m_base * D_DIM;
    const bf16* B1 = wb1t + ((size_t)e * F_DIM + (size_t)nt * 128) * D_DIM;
    const bf16* B3 = wb3t + ((size_t)e * F_DIM + (size_t)nt * 128) * D_DIM;

    const int lr16 = lane >> 2;
    const int cg   = lane & 3;
    const int srow = w * 32 + lr16;                        // staging row (j adds 16)
    const int scol = (cg ^ ((lr16 >> 1) & 3)) * 8;         // swizzled global col (elems)
    const int ldsbase = w * 1024;                          // elems (j adds 512)
    const int fm = lane & 15;
    const int fk = (((lane >> 4) ^ ((fm >> 1) & 3))) * 8;  // swizzled frag k-offset

    f32x4 acc1[4][4] = {};
    f32x4 acc3[4][4] = {};

    for (int kt = 0; kt < D_DIM / 32; ++kt) {
        const int k0 = kt * 32;
        #pragma unroll
        for (int j = 0; j < 2; ++j) {
            const size_t go = (size_t)(srow + j * 16) * D_DIM + (k0 + scol);
            gload_lds16(Ab + go, &As[ldsbase + j * 512]);
            gload_lds16(B1 + go, &Bs1[ldsbase + j * 512]);
            gload_lds16(B3 + go, &Bs3[ldsbase + j * 512]);
        }
        __syncthreads();
        bf16x8 af[4], b1f[4], b3f[4];
        #pragma unroll
        for (int i = 0; i < 4; ++i) {
            af[i]  = *(const bf16x8*)&As [(wm * 64 + i * 16 + fm) * 32 + fk];
            b1f[i] = *(const bf16x8*)&Bs1[(wn * 64 + i * 16 + fm) * 32 + fk];
            b3f[i] = *(const bf16x8*)&Bs3[(wn * 64 + i * 16 + fm) * 32 + fk];
        }
        #pragma unroll
        for (int i = 0; i < 4; ++i) {
            #pragma unroll
            for (int jn = 0; jn < 4; ++jn) {
                acc1[i][jn] = __builtin_amdgcn_mfma_f32_16x16x32_bf16(af[i], b1f[jn], acc1[i][jn], 0, 0, 0);
                acc3[i][jn] = __builtin_amdgcn_mfma_f32_16x16x32_bf16(af[i], b3f[jn], acc3[i][jn], 0, 0, 0);
            }
        }
        __syncthreads();
    }

    // epilogue: silu(s1)*s3 -> bf16  (C/D layout: col=lane&15, row=(lane>>4)*4+reg)
    unsigned short* hw = (unsigned short*)hb;
    #pragma unroll
    for (int i = 0; i < 4; ++i) {
        const int rbase = m_base + wm * 64 + i * 16 + (lane >> 4) * 4;
        #pragma unroll
        for (int jn = 0; jn < 4; ++jn) {
            const int col = nt * 128 + wn * 64 + jn * 16 + (lane & 15);
            #pragma unroll
            for (int r = 0; r < 4; ++r) {
                const float s1 = acc1[i][jn][r];
                const float s3 = acc3[i][jn][r];
                const float hv = (s1 / (1.0f + __expf(-s1))) * s3;
                hw[(size_t)(rbase + r) * F_DIM + col] = f2b(hv);
            }
        }
    }
}

// ---------------------------------------------------------------------------
// GEMM2: y = H @ W2 (per permuted row, fp32 out, no atomics)
//   hb [RCAP][F] bf16, wb2t [E][D][F] bf16 (B^T), yb [RCAP][D] fp32
// ---------------------------------------------------------------------------
__global__ __launch_bounds__(256, 2) void gemm2_kernel(const bf16* __restrict__ hb,
                                                       const bf16* __restrict__ wb2t,
                                                       float* __restrict__ yb,
                                                       const int* __restrict__ aoff,
                                                       const int* __restrict__ counts) {
    __shared__ bf16 As[128 * 32];
    __shared__ bf16 Bs[128 * 32];

    const int m_base = blockIdx.y * 128;
    int e = 0;
    #pragma unroll
    for (int i = 1; i < E_NUM; ++i) if (m_base >= aoff[i]) e = i;
    if (m_base - aoff[e] >= counts[e]) return;

    const int nt   = blockIdx.x;
    const int tid  = threadIdx.x;
    const int w    = tid >> 6;
    const int lane = tid & 63;
    const int wm   = w & 1, wn = w >> 1;

    const bf16* Ab = hb + (size_t)m_base * F_DIM;
    const bf16* Bb = wb2t + ((size_t)e * D_DIM + (size_t)nt * 128) * F_DIM;

    const int lr16 = lane >> 2;
    const int cg   = lane & 3;
    const int srow = w * 32 + lr16;
    const int scol = (cg ^ ((lr16 >> 1) & 3)) * 8;
    const int ldsbase = w * 1024;
    const int fm = lane & 15;
    const int fk = (((lane >> 4) ^ ((fm >> 1) & 3))) * 8;

    f32x4 acc[4][4] = {};

    for (int kt = 0; kt < F_DIM / 32; ++kt) {
        const int k0 = kt * 32;
        #pragma unroll
        for (int j = 0; j < 2; ++j) {
            const size_t go = (size_t)(srow + j * 16) * F_DIM + (k0 + scol);
            gload_lds16(Ab + go, &As[ldsbase + j * 512]);
            gload_lds16(Bb + go, &Bs[ldsbase + j * 512]);
        }
        __syncthreads();
        bf16x8 af[4], bfr[4];
        #pragma unroll
        for (int i = 0; i < 4; ++i) {
            af[i]  = *(const bf16x8*)&As[(wm * 64 + i * 16 + fm) * 32 + fk];
            bfr[i] = *(const bf16x8*)&Bs[(wn * 64 + i * 16 + fm) * 32 + fk];
        }
        #pragma unroll
        for (int i = 0; i < 4; ++i) {
            #pragma unroll
            for (int jn = 0; jn < 4; ++jn) {
                acc[i][jn] = __builtin_amdgcn_mfma_f32_16x16x32_bf16(af[i], bfr[jn], acc[i][jn], 0, 0, 0);
            }
        }
        __syncthreads();
    }

    #pragma unroll
    for (int i = 0; i < 4; ++i) {
        const int rb = m_base + wm * 64 + i * 16 + (lane >> 4) * 4;
        #pragma unroll
        for (int r = 0; r < 4; ++r) {
            float* yrow = yb + (size_t)(rb + r) * D_DIM;
            #pragma unroll
            for (int jn = 0; jn < 4; ++jn) {
                const int col = nt * 128 + wn * 64 + jn * 16 + (lane & 15);
                yrow[col] = acc[i][jn][r];
            }
        }
    }
}

// ---------------------------------------------------------------------------
// Combine: out[t] = w0*y[row0] + w1*y[row1]   (fully overwrites d_out)
// ---------------------------------------------------------------------------
__global__ __launch_bounds__(256) void combine_kernel(const float* __restrict__ yb,
                                                      const int* __restrict__ s2r,
                                                      const float* __restrict__ tkw,
                                                      float* __restrict__ out) {
    const int idx = blockIdx.x * 256 + threadIdx.x;   // one float4 per thread
    const int t = idx >> 8;                           // 256 float4 per token
    const int c = (idx & 255) * 4;
    const int r0 = s2r[t * 2], r1 = s2r[t * 2 + 1];
    const float w0 = tkw[t * 2], w1 = tkw[t * 2 + 1];
    const float4 a = *(const float4*)(yb + (size_t)r0 * D_DIM + c);
    const float4 b = *(const float4*)(yb + (size_t)r1 * D_DIM + c);
    float4 o;
    o.x = w0 * a.x + w1 * b.x;
    o.y = w0 * a.y + w1 * b.y;
    o.z = w0 * a.z + w1 * b.z;
    o.w = w0 * a.w + w1 * b.w;
    *(float4*)(out + (size_t)t * D_DIM + c) = o;
}

// ---------------------------------------------------------------------------
extern "C" void kernel_launch(void* const* d_in, const int* in_sizes, int n_in,
                              void* d_out, int out_size, void* d_ws, size_t ws_size,
                              hipStream_t stream) {
    const float* x  = (const float*)d_in[0];
    const float* gw = (const float*)d_in[1];
    const float* w1 = (const float*)d_in[2];
    const float* w3 = (const float*)d_in[3];
    const float* w2 = (const float*)d_in[4];
    float* out = (float*)d_out;

    char* ws = (char*)d_ws;
    size_t off = 0;
    bf16* wb1t = (bf16*)(ws + off);                      // [E][F][D]
    bf16* wb2t = wb1t;                                   // aliased: w2^T built after gemm1
    off += (size_t)E_NUM * F_DIM * D_DIM * 2;
    bf16* wb3t = (bf16*)(ws + off);                      // [E][F][D]
    float* yb  = (float*)wb3t;                           // aliased: wb3t+xp dead after gemm1
    off += (size_t)E_NUM * F_DIM * D_DIM * 2;
    bf16* xp   = (bf16*)(ws + off); off += (size_t)RCAP * D_DIM * 2;   // [RCAP][D]
    // (yb = [RCAP][D] fp32 = 71.3 MB fits in wb3t(67.1) + xp(35.7) = 102.8 MB)
    bf16* hb   = (bf16*)(ws + off); off += (size_t)RCAP * F_DIM * 2;   // [RCAP][F]
    int*   tki = (int*)(ws + off);   off += (size_t)T_TOK * 2 * 4;
    float* tkw = (float*)(ws + off); off += (size_t)T_TOK * 2 * 4;
    int* counts = (int*)(ws + off);  off += 64;
    int* cursor = (int*)(ws + off);  off += 64;
    int* aoff   = (int*)(ws + off);  off += 64;
    int* s2r    = (int*)(ws + off);  off += (size_t)T_TOK * 2 * 4;

    hipMemsetAsync(counts, 0, 64, stream);

    gate_kernel<<<T_TOK / 4, 256, 0, stream>>>(x, gw, tki, tkw, counts);
    scan_kernel<<<1, 64, 0, stream>>>(counts, aoff, cursor);
    gather_kernel<<<(T_TOK * 2) / 4, 256, 0, stream>>>(x, tki, cursor, s2r, xp);

    trans_kernel<<<dim3(F_DIM / 64, D_DIM / 64, E_NUM), 256, 0, stream>>>(w1, wb1t, D_DIM, F_DIM);
    trans_kernel<<<dim3(F_DIM / 64, D_DIM / 64, E_NUM), 256, 0, stream>>>(w3, wb3t, D_DIM, F_DIM);

    gemm1_kernel<<<dim3(F_DIM / 128, MT), 256, 0, stream>>>(xp, wb1t, wb3t, hb, aoff, counts);

    trans_kernel<<<dim3(D_DIM / 64, F_DIM / 64, E_NUM), 256, 0, stream>>>(w2, wb2t, F_DIM, D_DIM);

    gemm2_kernel<<<dim3(D_DIM / 128, MT), 256, 0, stream>>>(hb, wb2t, yb, aoff, counts);

    combine_kernel<<<(T_TOK * 256) / 256, 256, 0, stream>>>(yb, s2r, tkw, out);
}